// Round 1
// baseline (1549.447 us; speedup 1.0000x reference)
//
#include <hip/hip_runtime.h>
#include <hip/hip_bf16.h>

#define N_NODES 100000
#define N_EDGES 1600000
#define C_HID 32
#define C_OUT 8
#define N_AGENTS 1000

// ---------------- degree ----------------
__global__ void degree_kernel(const int* __restrict__ dst, float* __restrict__ cnt,
                              int n_edges) {
    int e = blockIdx.x * blockDim.x + threadIdx.x;
    if (e < n_edges) atomicAdd(&cnt[dst[e]], 1.0f);
}

__global__ void invert_kernel(float* __restrict__ cnt, int n) {
    int i = blockIdx.x * blockDim.x + threadIdx.x;
    if (i < n) cnt[i] = 1.0f / fmaxf(cnt[i], 1.0f);
}

// ---------------- scatter-add (mean numerator) ----------------
// gid -> (edge, 4-channel chunk). float4 gather from h[src], 4 atomics to agg[dst].
__global__ void scatter_kernel(const int* __restrict__ src, const int* __restrict__ dst,
                               const float* __restrict__ h, float* __restrict__ agg,
                               int n_edges, int dst_limit) {
    int gid = blockIdx.x * blockDim.x + threadIdx.x;
    int e = gid >> 3;
    if (e >= n_edges) return;
    int d = dst[e];
    if (d >= dst_limit) return;
    int s = src[e];
    int chunk = (gid & 7) << 2;
    float4 v = *reinterpret_cast<const float4*>(h + s * 32 + chunk);
    float* a = agg + d * 32 + chunk;
    atomicAdd(a + 0, v.x);
    atomicAdd(a + 1, v.y);
    atomicAdd(a + 2, v.z);
    atomicAdd(a + 3, v.w);
}

// ---------------- dense layer: h_out = relu(agg*inv @ Wl + bl + h @ Wr) ----------------
// 256 threads = 8 nodes x 32 out-channels. Weights staged in LDS.
__global__ void sage_dense_kernel(const float* __restrict__ agg,
                                  const float* __restrict__ inv,
                                  const float* __restrict__ h,
                                  const float* __restrict__ Wl,
                                  const float* __restrict__ bl,
                                  const float* __restrict__ Wr,
                                  float* __restrict__ out, int n_nodes) {
    __shared__ float sWl[1024];
    __shared__ float sWr[1024];
    __shared__ float sb[32];
    __shared__ float sAgg[256];
    __shared__ float sH[256];
    int tid = threadIdx.x;
    for (int i = tid; i < 1024; i += 256) { sWl[i] = Wl[i]; sWr[i] = Wr[i]; }
    if (tid < 32) sb[tid] = bl[tid];
    int base = blockIdx.x * 256;  // flat element base (8 nodes * 32)
    sAgg[tid] = agg[base + tid];
    sH[tid]   = h[base + tid];
    __syncthreads();
    int local = tid >> 5;               // node within block
    int node = blockIdx.x * 8 + local;  // global node
    int c = tid & 31;
    if (node >= n_nodes) return;
    float iv = inv[node];
    float acc = sb[c];
    int row = local << 5;
    #pragma unroll
    for (int k = 0; k < 32; k++) {
        acc += sAgg[row + k] * iv * sWl[(k << 5) + c] + sH[row + k] * sWr[(k << 5) + c];
    }
    out[(node << 5) + c] = fmaxf(acc, 0.0f);
}

// ---------------- final: h3 (1000 nodes) fused with W_out projection ----------------
__global__ void sage_final_kernel(const float* __restrict__ agg,
                                  const float* __restrict__ inv,
                                  const float* __restrict__ h,
                                  const float* __restrict__ Wl,
                                  const float* __restrict__ bl,
                                  const float* __restrict__ Wr,
                                  const float* __restrict__ Wout,
                                  const float* __restrict__ bout,
                                  float* __restrict__ out) {
    __shared__ float sWl[1024];
    __shared__ float sWr[1024];
    __shared__ float sb[32];
    __shared__ float sWo[256];   // 32x8
    __shared__ float sbo[8];
    __shared__ float sh3[8][33];
    int tid = threadIdx.x;
    for (int i = tid; i < 1024; i += 256) { sWl[i] = Wl[i]; sWr[i] = Wr[i]; }
    if (tid < 32) sb[tid] = bl[tid];
    if (tid < 256) { /* 32*8 = 256 exactly */ sWo[tid] = Wout[tid]; }
    if (tid < 8) sbo[tid] = bout[tid];
    __syncthreads();
    int local = tid >> 5;
    int node = blockIdx.x * 8 + local;  // 1000 nodes, 125 blocks -> always valid
    int c = tid & 31;
    float iv = inv[node];
    const float* ar = agg + (node << 5);
    const float* hr = h + (node << 5);
    float acc = sb[c];
    #pragma unroll
    for (int k = 0; k < 32; k++) {
        acc += ar[k] * iv * sWl[(k << 5) + c] + hr[k] * sWr[(k << 5) + c];
    }
    sh3[local][c] = fmaxf(acc, 0.0f);
    __syncthreads();
    if (c < 8) {
        float o = sbo[c];
        #pragma unroll
        for (int k = 0; k < 32; k++) o += sh3[local][k] * sWo[(k << 3) + c];
        out[node * 8 + c] = o;
    }
}

extern "C" void kernel_launch(void* const* d_in, const int* in_sizes, int n_in,
                              void* d_out, int out_size, void* d_ws, size_t ws_size,
                              hipStream_t stream) {
    const float* x   = (const float*)d_in[0];
    const int* ei    = (const int*)d_in[1];
    const float* Wl1 = (const float*)d_in[2];
    const float* bl1 = (const float*)d_in[3];
    const float* Wr1 = (const float*)d_in[4];
    const float* Wl2 = (const float*)d_in[5];
    const float* bl2 = (const float*)d_in[6];
    const float* Wr2 = (const float*)d_in[7];
    const float* Wl3 = (const float*)d_in[8];
    const float* bl3 = (const float*)d_in[9];
    const float* Wr3 = (const float*)d_in[10];
    const float* Wout = (const float*)d_in[11];
    const float* bout = (const float*)d_in[12];
    float* out = (float*)d_out;

    const int* src = ei;
    const int* dst = ei + N_EDGES;

    float* ws = (float*)d_ws;
    float* cnt_inv = ws;                         // 100000 floats
    float* agg = cnt_inv + N_NODES;              // 3.2M floats
    float* hA  = agg + (size_t)N_NODES * 32;     // 3.2M floats
    float* hB  = hA + (size_t)N_NODES * 32;      // 3.2M floats

    const size_t FEAT_BYTES = (size_t)N_NODES * 32 * sizeof(float);

    // degree -> reciprocal (once; reused by all layers)
    hipMemsetAsync(cnt_inv, 0, N_NODES * sizeof(float), stream);
    degree_kernel<<<(N_EDGES + 255) / 256, 256, 0, stream>>>(dst, cnt_inv, N_EDGES);
    invert_kernel<<<(N_NODES + 255) / 256, 256, 0, stream>>>(cnt_inv, N_NODES);

    const int scatter_blocks = (N_EDGES * 8 + 255) / 256;

    // ---- layer 1 ----
    hipMemsetAsync(agg, 0, FEAT_BYTES, stream);
    scatter_kernel<<<scatter_blocks, 256, 0, stream>>>(src, dst, x, agg, N_EDGES, N_NODES);
    sage_dense_kernel<<<(N_NODES + 7) / 8, 256, 0, stream>>>(agg, cnt_inv, x, Wl1, bl1, Wr1, hA, N_NODES);

    // ---- layer 2 ----
    hipMemsetAsync(agg, 0, FEAT_BYTES, stream);
    scatter_kernel<<<scatter_blocks, 256, 0, stream>>>(src, dst, hA, agg, N_EDGES, N_NODES);
    sage_dense_kernel<<<(N_NODES + 7) / 8, 256, 0, stream>>>(agg, cnt_inv, hA, Wl2, bl2, Wr2, hB, N_NODES);

    // ---- layer 3 (only dst < N_AGENTS matters) + output projection ----
    hipMemsetAsync(agg, 0, (size_t)N_AGENTS * 32 * sizeof(float), stream);
    scatter_kernel<<<scatter_blocks, 256, 0, stream>>>(src, dst, hB, agg, N_EDGES, N_AGENTS);
    sage_final_kernel<<<N_AGENTS / 8, 256, 0, stream>>>(agg, cnt_inv, hB, Wl3, bl3, Wr3, Wout, bout, out);
}

// Round 2
// 429.961 us; speedup vs baseline: 3.6037x; 3.6037x over previous
//
#include <hip/hip_runtime.h>
#include <hip/hip_bf16.h>

#define N_NODES 100000
#define N_EDGES 1600000
#define C_HID 32
#define C_OUT 8
#define N_AGENTS 1000

#define SCAN_BLOCK 256
#define N_SCAN_BLOCKS ((N_NODES + SCAN_BLOCK - 1) / SCAN_BLOCK)   // 391

// ---------------- degree (int atomics) ----------------
__global__ void degree_kernel(const int* __restrict__ dst, int* __restrict__ cnt) {
    int e = blockIdx.x * blockDim.x + threadIdx.x;
    if (e < N_EDGES) atomicAdd(&cnt[dst[e]], 1);
}

// ---------------- scan pass 1: per-block exclusive scan + block sums ----------------
__global__ void scan1_kernel(const int* __restrict__ cnt, int* __restrict__ rowptr,
                             int* __restrict__ bsum) {
    __shared__ int tmp[SCAN_BLOCK];
    int i = blockIdx.x * SCAN_BLOCK + threadIdx.x;
    int v = (i < N_NODES) ? cnt[i] : 0;
    tmp[threadIdx.x] = v;
    __syncthreads();
    for (int off = 1; off < SCAN_BLOCK; off <<= 1) {
        int u = (threadIdx.x >= off) ? tmp[threadIdx.x - off] : 0;
        __syncthreads();
        tmp[threadIdx.x] += u;
        __syncthreads();
    }
    if (i < N_NODES) rowptr[i] = tmp[threadIdx.x] - v;   // exclusive within block
    if (threadIdx.x == SCAN_BLOCK - 1) bsum[blockIdx.x] = tmp[SCAN_BLOCK - 1];
}

// ---------------- scan pass 2: exclusive scan of block sums (single block) ----------------
__global__ void scan2_kernel(int* __restrict__ bsum) {
    __shared__ int tmp[512];
    int t = threadIdx.x;
    int v = (t < N_SCAN_BLOCKS) ? bsum[t] : 0;
    tmp[t] = v;
    __syncthreads();
    for (int off = 1; off < 512; off <<= 1) {
        int u = (t >= off) ? tmp[t - off] : 0;
        __syncthreads();
        tmp[t] += u;
        __syncthreads();
    }
    if (t < N_SCAN_BLOCKS) bsum[t] = tmp[t] - v;         // exclusive
}

// ---------------- scan pass 3: add offsets; also emit inv-degree and zero cursors ----------------
__global__ void scan3_kernel(const int* __restrict__ cnt, int* __restrict__ rowptr,
                             const int* __restrict__ bsum, float* __restrict__ inv,
                             int* __restrict__ cursor) {
    int i = blockIdx.x * SCAN_BLOCK + threadIdx.x;
    if (i == 0) rowptr[N_NODES] = N_EDGES;
    if (i >= N_NODES) return;
    rowptr[i] += bsum[blockIdx.x];
    inv[i] = 1.0f / fmaxf((float)cnt[i], 1.0f);
    cursor[i] = 0;
}

// ---------------- permute edges into CSR order (int atomics on cursors) ----------------
__global__ void permute_kernel(const int* __restrict__ src, const int* __restrict__ dst,
                               const int* __restrict__ rowptr, int* __restrict__ cursor,
                               int* __restrict__ esrc) {
    int e = blockIdx.x * blockDim.x + threadIdx.x;
    if (e >= N_EDGES) return;
    int d = dst[e];
    int pos = rowptr[d] + atomicAdd(&cursor[d], 1);
    esrc[pos] = src[e];
}

// ---------------- fused SAGE layer: gather-aggregate + dense + ReLU ----------------
// One wave (64 lanes) per dst node. Halves (32 lanes) each handle one neighbor
// per step, lane = channel. Epilogue: half0 computes mean@Wl, half1 computes
// h@Wr via shuffle-broadcast; combined with shfl_xor(32).
__global__ __launch_bounds__(256) void sage_layer_kernel(
    const int* __restrict__ rowptr, const int* __restrict__ esrc,
    const float* __restrict__ inv, const float* __restrict__ h,
    const float* __restrict__ Wl, const float* __restrict__ bl,
    const float* __restrict__ Wr, float* __restrict__ out, int n_nodes)
{
    __shared__ float sWl[1024], sWr[1024], sb[32];
    int tid = threadIdx.x;
    for (int i = tid; i < 1024; i += 256) { sWl[i] = Wl[i]; sWr[i] = Wr[i]; }
    if (tid < 32) sb[tid] = bl[tid];
    __syncthreads();

    int wave = tid >> 6;
    int lane = tid & 63;
    int half = lane >> 5;            // 0 or 1
    int c = lane & 31;               // channel
    int node = blockIdx.x * 4 + wave;
    if (node >= n_nodes) return;

    int beg = rowptr[node], end = rowptr[node + 1];

    // gather-accumulate: 2 neighbors per wave-step, unrolled x2 for MLP
    float acc0 = 0.f, acc1 = 0.f;
    int j = beg + half;
    for (; j + 2 < end; j += 4) {
        int s0 = esrc[j];
        int s1 = esrc[j + 2];
        acc0 += h[s0 * 32 + c];
        acc1 += h[s1 * 32 + c];
    }
    if (j < end) acc0 += h[esrc[j] * 32 + c];
    float acc = acc0 + acc1;
    acc += __shfl_xor(acc, 32);      // both halves now hold full channel sum

    float mean = acc * inv[node];
    float hv = h[node * 32 + c];

    // half0: sum_k mean_k * Wl[k][c]; half1: sum_k h_k * Wr[k][c]
    float op = half ? hv : mean;
    const float* W = half ? sWr : sWl;
    int srcl_base = half << 5;
    float t = 0.f;
    #pragma unroll
    for (int k = 0; k < 32; k++) {
        float v = __shfl(op, srcl_base + k);
        t += v * W[(k << 5) + c];
    }
    t += __shfl_xor(t, 32);
    if (half == 0) out[node * 32 + c] = fmaxf(t + sb[c], 0.0f);
}

// ---------------- output projection: first 1000 nodes, 32 -> 8 ----------------
__global__ void out_proj_kernel(const float* __restrict__ h3,
                                const float* __restrict__ Wout,
                                const float* __restrict__ bout,
                                float* __restrict__ out) {
    __shared__ float sWo[256];
    __shared__ float sbo[8];
    int tid = threadIdx.x;
    sWo[tid] = Wout[tid];
    if (tid < 8) sbo[tid] = bout[tid];
    __syncthreads();
    int node = blockIdx.x * 32 + (tid >> 3);
    int c = tid & 7;
    if (node >= N_AGENTS) return;
    float o = sbo[c];
    const float* hr = h3 + node * 32;
    #pragma unroll
    for (int k = 0; k < 32; k++) o += hr[k] * sWo[(k << 3) + c];
    out[node * 8 + c] = o;
}

extern "C" void kernel_launch(void* const* d_in, const int* in_sizes, int n_in,
                              void* d_out, int out_size, void* d_ws, size_t ws_size,
                              hipStream_t stream) {
    const float* x   = (const float*)d_in[0];
    const int* ei    = (const int*)d_in[1];
    const float* Wl1 = (const float*)d_in[2];
    const float* bl1 = (const float*)d_in[3];
    const float* Wr1 = (const float*)d_in[4];
    const float* Wl2 = (const float*)d_in[5];
    const float* bl2 = (const float*)d_in[6];
    const float* Wr2 = (const float*)d_in[7];
    const float* Wl3 = (const float*)d_in[8];
    const float* bl3 = (const float*)d_in[9];
    const float* Wr3 = (const float*)d_in[10];
    const float* Wout = (const float*)d_in[11];
    const float* bout = (const float*)d_in[12];
    float* out = (float*)d_out;

    const int* src = ei;
    const int* dst = ei + N_EDGES;

    // workspace layout (all 4-byte types)
    char* ws = (char*)d_ws;
    int*   cnt    = (int*)ws;                                  ws += (size_t)N_NODES * 4;
    int*   rowptr = (int*)ws;                                  ws += (size_t)(N_NODES + 8) * 4;
    int*   cursor = (int*)ws;                                  ws += (size_t)N_NODES * 4;
    float* inv    = (float*)ws;                                ws += (size_t)N_NODES * 4;
    int*   bsum   = (int*)ws;                                  ws += 512 * 4;
    int*   esrc   = (int*)ws;                                  ws += (size_t)N_EDGES * 4;
    float* hA     = (float*)ws;                                ws += (size_t)N_NODES * 32 * 4;
    float* hB     = (float*)ws;

    // ---- CSR build ----
    hipMemsetAsync(cnt, 0, N_NODES * sizeof(int), stream);
    degree_kernel<<<(N_EDGES + 255) / 256, 256, 0, stream>>>(dst, cnt);
    scan1_kernel<<<N_SCAN_BLOCKS, SCAN_BLOCK, 0, stream>>>(cnt, rowptr, bsum);
    scan2_kernel<<<1, 512, 0, stream>>>(bsum);
    scan3_kernel<<<N_SCAN_BLOCKS, SCAN_BLOCK, 0, stream>>>(cnt, rowptr, bsum, inv, cursor);
    permute_kernel<<<(N_EDGES + 255) / 256, 256, 0, stream>>>(src, dst, rowptr, cursor, esrc);

    // ---- layers (fused aggregate + dense + ReLU) ----
    sage_layer_kernel<<<(N_NODES + 3) / 4, 256, 0, stream>>>(
        rowptr, esrc, inv, x, Wl1, bl1, Wr1, hA, N_NODES);
    sage_layer_kernel<<<(N_NODES + 3) / 4, 256, 0, stream>>>(
        rowptr, esrc, inv, hA, Wl2, bl2, Wr2, hB, N_NODES);
    // layer 3: only nodes < N_AGENTS are needed downstream
    sage_layer_kernel<<<(N_AGENTS + 3) / 4, 256, 0, stream>>>(
        rowptr, esrc, inv, hB, Wl3, bl3, Wr3, hA, N_AGENTS);
    out_proj_kernel<<<(N_AGENTS + 31) / 32, 256, 0, stream>>>(hA, Wout, bout, out);
}

// Round 3
// 340.973 us; speedup vs baseline: 4.5442x; 1.2610x over previous
//
#include <hip/hip_runtime.h>
#include <hip/hip_bf16.h>

#define N_NODES 100000
#define N_EDGES 1600000
#define N_AGENTS 1000

#define SCAN_BLOCK 256
#define N_SCAN_BLOCKS ((N_NODES + SCAN_BLOCK - 1) / SCAN_BLOCK)   // 391
#define LAYER_BLOCKS 2048

// ---------------- degree + per-edge rank (one atomic pass) ----------------
__global__ void degree_rank_kernel(const int* __restrict__ dst, int* __restrict__ cnt,
                                   int* __restrict__ rank) {
    int e = blockIdx.x * blockDim.x + threadIdx.x;
    if (e < N_EDGES) rank[e] = atomicAdd(&cnt[dst[e]], 1);
}

// ---------------- scan pass 1: per-block exclusive scan + block sums ----------------
__global__ void scan1_kernel(const int* __restrict__ cnt, int* __restrict__ rowptr,
                             int* __restrict__ bsum) {
    __shared__ int tmp[SCAN_BLOCK];
    int i = blockIdx.x * SCAN_BLOCK + threadIdx.x;
    int v = (i < N_NODES) ? cnt[i] : 0;
    tmp[threadIdx.x] = v;
    __syncthreads();
    for (int off = 1; off < SCAN_BLOCK; off <<= 1) {
        int u = (threadIdx.x >= off) ? tmp[threadIdx.x - off] : 0;
        __syncthreads();
        tmp[threadIdx.x] += u;
        __syncthreads();
    }
    if (i < N_NODES) rowptr[i] = tmp[threadIdx.x] - v;   // exclusive within block
    if (threadIdx.x == SCAN_BLOCK - 1) bsum[blockIdx.x] = tmp[SCAN_BLOCK - 1];
}

// ---------------- scan pass 2: exclusive scan of block sums (single block) ----------------
__global__ void scan2_kernel(int* __restrict__ bsum) {
    __shared__ int tmp[512];
    int t = threadIdx.x;
    int v = (t < N_SCAN_BLOCKS) ? bsum[t] : 0;
    tmp[t] = v;
    __syncthreads();
    for (int off = 1; off < 512; off <<= 1) {
        int u = (t >= off) ? tmp[t - off] : 0;
        __syncthreads();
        tmp[t] += u;
        __syncthreads();
    }
    if (t < N_SCAN_BLOCKS) bsum[t] = tmp[t] - v;         // exclusive
}

// ---------------- scan pass 3: add offsets; emit inv-degree ----------------
__global__ void scan3_kernel(const int* __restrict__ cnt, int* __restrict__ rowptr,
                             const int* __restrict__ bsum, float* __restrict__ inv) {
    int i = blockIdx.x * SCAN_BLOCK + threadIdx.x;
    if (i == 0) rowptr[N_NODES] = N_EDGES;
    if (i >= N_NODES) return;
    rowptr[i] += bsum[blockIdx.x];
    inv[i] = 1.0f / fmaxf((float)cnt[i], 1.0f);
}

// ---------------- permute edges into CSR order (no atomics, no dep chain) ----------------
__global__ void permute_kernel(const int* __restrict__ src, const int* __restrict__ dst,
                               const int* __restrict__ rank, const int* __restrict__ rowptr,
                               int* __restrict__ esrc) {
    int e = blockIdx.x * blockDim.x + threadIdx.x;
    if (e >= N_EDGES) return;
    int d = dst[e];
    esrc[rowptr[d] + rank[e]] = src[e];
}

// ---------------- fused SAGE layer: gather-aggregate + dense + ReLU ----------------
// One wave per dst node (grid-strided). Lane = (slot 0..7, quad 0..7):
// 8 neighbors in flight, each gathered as float4 by 8 lanes (full 128B row per
// neighbor per instruction). Slot-reduce via shfl_xor; dense epilogue via
// shuffle-broadcast: half0 computes mean@Wl, half1 computes h@Wr.
__global__ __launch_bounds__(256) void sage_layer_kernel(
    const int* __restrict__ rowptr, const int* __restrict__ esrc,
    const float* __restrict__ inv, const float* __restrict__ h,
    const float* __restrict__ Wl, const float* __restrict__ bl,
    const float* __restrict__ Wr, float* __restrict__ out, int n_nodes)
{
    __shared__ float sWl[1024], sWr[1024], sb[32];
    int tid = threadIdx.x;
    for (int i = tid; i < 1024; i += 256) { sWl[i] = Wl[i]; sWr[i] = Wr[i]; }
    if (tid < 32) sb[tid] = bl[tid];
    __syncthreads();

    int lane = tid & 63;
    int wave = tid >> 6;
    int slot = lane >> 3;            // neighbor slot 0..7
    int quad = lane & 7;             // channel quad 0..7
    int half = lane >> 5;            // epilogue: 0 -> Wl path, 1 -> Wr path
    int c = lane & 31;               // epilogue: output channel
    int stride = gridDim.x * 4;

    for (int node = blockIdx.x * 4 + wave; node < n_nodes; node += stride) {
        int beg = rowptr[node], end = rowptr[node + 1];
        float4 acc = {0.f, 0.f, 0.f, 0.f};
        for (int j = beg + slot; j < end; j += 8) {
            int s = esrc[j];
            float4 v = *reinterpret_cast<const float4*>(h + s * 32 + quad * 4);
            acc.x += v.x; acc.y += v.y; acc.z += v.z; acc.w += v.w;
        }
        // reduce over the 8 slots (quads aligned: lanes with equal (lane&7))
        #pragma unroll
        for (int m = 8; m <= 32; m <<= 1) {
            acc.x += __shfl_xor(acc.x, m);
            acc.y += __shfl_xor(acc.y, m);
            acc.z += __shfl_xor(acc.z, m);
            acc.w += __shfl_xor(acc.w, m);
        }
        float iv = inv[node];
        float4 hv = *reinterpret_cast<const float4*>(h + node * 32 + quad * 4);
        // half0 lanes carry mean, half1 lanes carry self features
        float o0, o1, o2, o3;
        if (half == 0) { o0 = acc.x * iv; o1 = acc.y * iv; o2 = acc.z * iv; o3 = acc.w * iv; }
        else           { o0 = hv.x;       o1 = hv.y;       o2 = hv.z;       o3 = hv.w; }
        const float* W = half ? sWr : sWl;
        int sl_base = half << 5;     // fetch mean from lanes 0..7, self from 32..39
        float t = 0.f;
        #pragma unroll
        for (int k = 0; k < 32; k++) {
            float comp = ((k & 3) == 0) ? o0 : ((k & 3) == 1) ? o1 : ((k & 3) == 2) ? o2 : o3;
            float v = __shfl(comp, sl_base + (k >> 2));
            t += v * W[(k << 5) + c];
        }
        t += __shfl_xor(t, 32);      // combine Wl-part and Wr-part
        if (half == 0) out[node * 32 + c] = fmaxf(t + sb[c], 0.0f);
    }
}

// ---------------- output projection: first 1000 nodes, 32 -> 8 ----------------
__global__ void out_proj_kernel(const float* __restrict__ h3,
                                const float* __restrict__ Wout,
                                const float* __restrict__ bout,
                                float* __restrict__ out) {
    __shared__ float sWo[256];
    __shared__ float sbo[8];
    int tid = threadIdx.x;
    sWo[tid] = Wout[tid];
    if (tid < 8) sbo[tid] = bout[tid];
    __syncthreads();
    int node = blockIdx.x * 32 + (tid >> 3);
    int c = tid & 7;
    if (node >= N_AGENTS) return;
    float o = sbo[c];
    const float* hr = h3 + node * 32;
    #pragma unroll
    for (int k = 0; k < 32; k++) o += hr[k] * sWo[(k << 3) + c];
    out[node * 8 + c] = o;
}

extern "C" void kernel_launch(void* const* d_in, const int* in_sizes, int n_in,
                              void* d_out, int out_size, void* d_ws, size_t ws_size,
                              hipStream_t stream) {
    const float* x   = (const float*)d_in[0];
    const int* ei    = (const int*)d_in[1];
    const float* Wl1 = (const float*)d_in[2];
    const float* bl1 = (const float*)d_in[3];
    const float* Wr1 = (const float*)d_in[4];
    const float* Wl2 = (const float*)d_in[5];
    const float* bl2 = (const float*)d_in[6];
    const float* Wr2 = (const float*)d_in[7];
    const float* Wl3 = (const float*)d_in[8];
    const float* bl3 = (const float*)d_in[9];
    const float* Wr3 = (const float*)d_in[10];
    const float* Wout = (const float*)d_in[11];
    const float* bout = (const float*)d_in[12];
    float* out = (float*)d_out;

    const int* src = ei;
    const int* dst = ei + N_EDGES;

    // workspace layout
    char* ws = (char*)d_ws;
    int*   cnt    = (int*)ws;                                  ws += (size_t)N_NODES * 4;
    int*   rowptr = (int*)ws;                                  ws += (size_t)(N_NODES + 8) * 4;
    float* inv    = (float*)ws;                                ws += (size_t)N_NODES * 4;
    int*   bsum   = (int*)ws;                                  ws += 512 * 4;
    int*   esrc   = (int*)ws;                                  ws += (size_t)N_EDGES * 4;
    float* hA     = (float*)ws;                                ws += (size_t)N_NODES * 32 * 4;
    float* hB     = (float*)ws;
    int*   rank   = (int*)hA;   // dead before layer 1 writes hA

    // ---- CSR build ----
    hipMemsetAsync(cnt, 0, N_NODES * sizeof(int), stream);
    degree_rank_kernel<<<(N_EDGES + 255) / 256, 256, 0, stream>>>(dst, cnt, rank);
    scan1_kernel<<<N_SCAN_BLOCKS, SCAN_BLOCK, 0, stream>>>(cnt, rowptr, bsum);
    scan2_kernel<<<1, 512, 0, stream>>>(bsum);
    scan3_kernel<<<N_SCAN_BLOCKS, SCAN_BLOCK, 0, stream>>>(cnt, rowptr, bsum, inv);
    permute_kernel<<<(N_EDGES + 255) / 256, 256, 0, stream>>>(src, dst, rank, rowptr, esrc);

    // ---- layers (fused aggregate + dense + ReLU) ----
    sage_layer_kernel<<<LAYER_BLOCKS, 256, 0, stream>>>(
        rowptr, esrc, inv, x, Wl1, bl1, Wr1, hA, N_NODES);
    sage_layer_kernel<<<LAYER_BLOCKS, 256, 0, stream>>>(
        rowptr, esrc, inv, hA, Wl2, bl2, Wr2, hB, N_NODES);
    // layer 3: only nodes < N_AGENTS are needed downstream
    sage_layer_kernel<<<(N_AGENTS + 3) / 4, 256, 0, stream>>>(
        rowptr, esrc, inv, hB, Wl3, bl3, Wr3, hA, N_AGENTS);
    out_proj_kernel<<<(N_AGENTS + 31) / 32, 256, 0, stream>>>(hA, Wout, bout, out);
}

// Round 4
// 285.590 us; speedup vs baseline: 5.4254x; 1.1939x over previous
//
#include <hip/hip_runtime.h>
#include <hip/hip_bf16.h>

#define N_NODES 100000
#define N_EDGES 1600000
#define N_AGENTS 1000

#define SCAN_BLOCK 256
#define N_SCAN_BLOCKS ((N_NODES + SCAN_BLOCK - 1) / SCAN_BLOCK)   // 391
#define AGG_BLOCKS 2048

typedef short s16x8 __attribute__((ext_vector_type(8)));
typedef float f32x4 __attribute__((ext_vector_type(4)));

// float -> bf16 round-to-nearest-even
__device__ __forceinline__ unsigned short f2bf(float f) {
    unsigned u = __float_as_uint(f);
    u += 0x7fffu + ((u >> 16) & 1u);
    return (unsigned short)(u >> 16);
}
__device__ __forceinline__ float bflo(unsigned u) { return __uint_as_float(u << 16); }
__device__ __forceinline__ float bfhi(unsigned u) { return __uint_as_float(u & 0xffff0000u); }

// ---------------- degree + per-edge rank (one atomic pass) ----------------
__global__ void degree_rank_kernel(const int* __restrict__ dst, int* __restrict__ cnt,
                                   int* __restrict__ rank) {
    int e = blockIdx.x * blockDim.x + threadIdx.x;
    if (e < N_EDGES) rank[e] = atomicAdd(&cnt[dst[e]], 1);
}

// ---------------- scan pass 1 ----------------
__global__ void scan1_kernel(const int* __restrict__ cnt, int* __restrict__ rowptr,
                             int* __restrict__ bsum) {
    __shared__ int tmp[SCAN_BLOCK];
    int i = blockIdx.x * SCAN_BLOCK + threadIdx.x;
    int v = (i < N_NODES) ? cnt[i] : 0;
    tmp[threadIdx.x] = v;
    __syncthreads();
    for (int off = 1; off < SCAN_BLOCK; off <<= 1) {
        int u = (threadIdx.x >= off) ? tmp[threadIdx.x - off] : 0;
        __syncthreads();
        tmp[threadIdx.x] += u;
        __syncthreads();
    }
    if (i < N_NODES) rowptr[i] = tmp[threadIdx.x] - v;
    if (threadIdx.x == SCAN_BLOCK - 1) bsum[blockIdx.x] = tmp[SCAN_BLOCK - 1];
}

// ---------------- scan pass 2 ----------------
__global__ void scan2_kernel(int* __restrict__ bsum) {
    __shared__ int tmp[512];
    int t = threadIdx.x;
    int v = (t < N_SCAN_BLOCKS) ? bsum[t] : 0;
    tmp[t] = v;
    __syncthreads();
    for (int off = 1; off < 512; off <<= 1) {
        int u = (t >= off) ? tmp[t - off] : 0;
        __syncthreads();
        tmp[t] += u;
        __syncthreads();
    }
    if (t < N_SCAN_BLOCKS) bsum[t] = tmp[t] - v;
}

// ---------------- scan pass 3: add offsets; emit inv-degree ----------------
__global__ void scan3_kernel(const int* __restrict__ cnt, int* __restrict__ rowptr,
                             const int* __restrict__ bsum, float* __restrict__ inv) {
    int i = blockIdx.x * SCAN_BLOCK + threadIdx.x;
    if (i == 0) rowptr[N_NODES] = N_EDGES;
    if (i >= N_NODES) return;
    rowptr[i] += bsum[blockIdx.x];
    inv[i] = 1.0f / fmaxf((float)cnt[i], 1.0f);
}

// ---------------- permute edges into CSR order ----------------
__global__ void permute_kernel(const int* __restrict__ src, const int* __restrict__ dst,
                               const int* __restrict__ rank, const int* __restrict__ rowptr,
                               int* __restrict__ esrc) {
    int e = blockIdx.x * blockDim.x + threadIdx.x;
    if (e >= N_EDGES) return;
    int d = dst[e];
    esrc[rowptr[d] + rank[e]] = src[e];
}

// ---------------- convert x (fp32) -> bf16 ----------------
__global__ void convert_x_kernel(const float* __restrict__ x, unsigned short* __restrict__ xb) {
    int i = blockIdx.x * blockDim.x + threadIdx.x;        // one float4 per thread
    if (i >= N_NODES * 32 / 4) return;
    float4 v = ((const float4*)x)[i];
    ushort4 o = make_ushort4(f2bf(v.x), f2bf(v.y), f2bf(v.z), f2bf(v.w));
    ((ushort4*)xb)[i] = o;
}

// ---------------- convert weights -> bf16, stacked [64 k][32 n] per layer ----------------
__global__ void prep_w_kernel(const float* __restrict__ Wl1, const float* __restrict__ Wr1,
                              const float* __restrict__ Wl2, const float* __restrict__ Wr2,
                              const float* __restrict__ Wl3, const float* __restrict__ Wr3,
                              unsigned short* __restrict__ Wcat) {
    int gid = blockIdx.x * blockDim.x + threadIdx.x;
    if (gid >= 3 * 2048) return;
    int L = gid >> 11, idx = gid & 2047;
    int k = idx >> 5, n = idx & 31;
    const float* Wl = (L == 0) ? Wl1 : (L == 1) ? Wl2 : Wl3;
    const float* Wr = (L == 0) ? Wr1 : (L == 1) ? Wr2 : Wr3;
    float v = (k < 32) ? Wl[k * 32 + n] : Wr[(k - 32) * 32 + n];
    Wcat[gid] = f2bf(v);
}

// ---------------- aggregate: mean of bf16 neighbor rows (fp32 acc) -> bf16 mean ----------------
// One wave per node; lane = (slot 0..7, quad 0..7); 8 neighbors in flight,
// each row (64 B) gathered by 8 lanes as uint2 (8 B = 4 bf16 channels).
__global__ __launch_bounds__(256) void aggregate_kernel(
    const int* __restrict__ rowptr, const int* __restrict__ esrc,
    const float* __restrict__ inv, const unsigned short* __restrict__ hb,
    unsigned short* __restrict__ meanb, int n_nodes)
{
    int tid = threadIdx.x;
    int lane = tid & 63, wave = tid >> 6;
    int slot = lane >> 3, q = lane & 7;
    int stride = gridDim.x * 4;
    for (int node = blockIdx.x * 4 + wave; node < n_nodes; node += stride) {
        int beg = rowptr[node], end = rowptr[node + 1];
        float a0 = 0.f, a1 = 0.f, a2 = 0.f, a3 = 0.f;
        for (int j = beg + slot; j < end; j += 8) {
            int s = esrc[j];
            uint2 u = *(const uint2*)(hb + s * 32 + q * 4);
            a0 += bflo(u.x); a1 += bfhi(u.x);
            a2 += bflo(u.y); a3 += bfhi(u.y);
        }
        #pragma unroll
        for (int m = 8; m <= 32; m <<= 1) {
            a0 += __shfl_xor(a0, m);
            a1 += __shfl_xor(a1, m);
            a2 += __shfl_xor(a2, m);
            a3 += __shfl_xor(a3, m);
        }
        if (lane < 8) {   // lane == quad q: holds channels 4q..4q+3
            float iv = inv[node];
            ushort4 o = make_ushort4(f2bf(a0 * iv), f2bf(a1 * iv), f2bf(a2 * iv), f2bf(a3 * iv));
            *(ushort4*)(meanb + node * 32 + lane * 4) = o;   // 8 lanes x 8B = 64B coalesced
        }
    }
}

// ---------------- dense: out = relu(cat(mean,self) @ Wcat + b) via MFMA ----------------
// Wave computes a 16-node x 32-channel tile: 2 N-tiles x 2 K-steps = 4 MFMAs.
// A layout: A[m=lane&15][k=quad*8+j]; C/D: col=lane&15, row=quad*4+reg.
__global__ __launch_bounds__(256) void dense_kernel(
    const unsigned short* __restrict__ meanb, const unsigned short* __restrict__ selfb,
    const unsigned short* __restrict__ Wcat, const float* __restrict__ bl,
    void* __restrict__ outp, int n_nodes, int out_f32)
{
    int tid = threadIdx.x;
    int lane = tid & 63, wave = tid >> 6;
    int l15 = lane & 15, quad = lane >> 4;

    // B frags: B[k][n], lane holds n=lane&15 (+16*nt), k=quad*8+j (+32*kt)
    s16x8 bf[2][2];
    #pragma unroll
    for (int kt = 0; kt < 2; kt++)
        #pragma unroll
        for (int nt = 0; nt < 2; nt++)
            #pragma unroll
            for (int j = 0; j < 8; j++) {
                int k = kt * 32 + quad * 8 + j;
                bf[kt][nt][j] = (short)Wcat[k * 32 + l15 + nt * 16];
            }
    float bias0 = bl[l15], bias1 = bl[l15 + 16];

    int ntiles = (n_nodes + 15) >> 4;
    for (int tile = blockIdx.x * 4 + wave; tile < ntiles; tile += gridDim.x * 4) {
        int node = tile * 16 + l15;
        int na = min(node, n_nodes - 1);
        s16x8 am = *(const s16x8*)(meanb + na * 32 + quad * 8);
        s16x8 as = *(const s16x8*)(selfb + na * 32 + quad * 8);
        f32x4 acc0 = {0.f, 0.f, 0.f, 0.f};
        f32x4 acc1 = {0.f, 0.f, 0.f, 0.f};
        acc0 = __builtin_amdgcn_mfma_f32_16x16x32_bf16(am, bf[0][0], acc0, 0, 0, 0);
        acc0 = __builtin_amdgcn_mfma_f32_16x16x32_bf16(as, bf[1][0], acc0, 0, 0, 0);
        acc1 = __builtin_amdgcn_mfma_f32_16x16x32_bf16(am, bf[0][1], acc1, 0, 0, 0);
        acc1 = __builtin_amdgcn_mfma_f32_16x16x32_bf16(as, bf[1][1], acc1, 0, 0, 0);
        #pragma unroll
        for (int r = 0; r < 4; r++) {
            int onode = tile * 16 + quad * 4 + r;
            if (onode < n_nodes) {
                float v0 = fmaxf(acc0[r] + bias0, 0.f);
                float v1 = fmaxf(acc1[r] + bias1, 0.f);
                if (out_f32) {
                    ((float*)outp)[onode * 32 + l15]      = v0;
                    ((float*)outp)[onode * 32 + l15 + 16] = v1;
                } else {
                    ((unsigned short*)outp)[onode * 32 + l15]      = f2bf(v0);
                    ((unsigned short*)outp)[onode * 32 + l15 + 16] = f2bf(v1);
                }
            }
        }
    }
}

// ---------------- output projection: first 1000 nodes, 32 -> 8 (fp32) ----------------
__global__ void out_proj_kernel(const float* __restrict__ h3,
                                const float* __restrict__ Wout,
                                const float* __restrict__ bout,
                                float* __restrict__ out) {
    __shared__ float sWo[256];
    __shared__ float sbo[8];
    int tid = threadIdx.x;
    sWo[tid] = Wout[tid];
    if (tid < 8) sbo[tid] = bout[tid];
    __syncthreads();
    int node = blockIdx.x * 32 + (tid >> 3);
    int c = tid & 7;
    if (node >= N_AGENTS) return;
    float o = sbo[c];
    const float* hr = h3 + node * 32;
    #pragma unroll
    for (int k = 0; k < 32; k++) o += hr[k] * sWo[(k << 3) + c];
    out[node * 8 + c] = o;
}

extern "C" void kernel_launch(void* const* d_in, const int* in_sizes, int n_in,
                              void* d_out, int out_size, void* d_ws, size_t ws_size,
                              hipStream_t stream) {
    const float* x   = (const float*)d_in[0];
    const int* ei    = (const int*)d_in[1];
    const float* Wl1 = (const float*)d_in[2];
    const float* bl1 = (const float*)d_in[3];
    const float* Wr1 = (const float*)d_in[4];
    const float* Wl2 = (const float*)d_in[5];
    const float* bl2 = (const float*)d_in[6];
    const float* Wr2 = (const float*)d_in[7];
    const float* Wl3 = (const float*)d_in[8];
    const float* bl3 = (const float*)d_in[9];
    const float* Wr3 = (const float*)d_in[10];
    const float* Wout = (const float*)d_in[11];
    const float* bout = (const float*)d_in[12];
    float* out = (float*)d_out;

    const int* src = ei;
    const int* dst = ei + N_EDGES;

    // workspace layout
    char* ws = (char*)d_ws;
    int*   cnt    = (int*)ws;                                  ws += (size_t)N_NODES * 4;
    int*   rowptr = (int*)ws;                                  ws += (size_t)(N_NODES + 8) * 4;
    float* inv    = (float*)ws;                                ws += (size_t)N_NODES * 4;
    int*   bsum   = (int*)ws;                                  ws += 512 * 4;
    int*   esrc   = (int*)ws;                                  ws += (size_t)N_EDGES * 4;
    unsigned short* meanb = (unsigned short*)ws;               ws += (size_t)N_NODES * 32 * 2;
    unsigned short* hXb   = (unsigned short*)ws;               ws += (size_t)N_NODES * 32 * 2;
    unsigned short* hAb   = (unsigned short*)ws;               ws += (size_t)N_NODES * 32 * 2;
    unsigned short* hBb   = (unsigned short*)ws;               ws += (size_t)N_NODES * 32 * 2;
    unsigned short* Wcat  = (unsigned short*)ws;               ws += 3 * 2048 * 2;
    float* h3f    = (float*)ws;                                ws += (size_t)N_AGENTS * 32 * 4;
    int*   rank   = (int*)meanb;   // 6.4MB alias: rank dead before layer-1 aggregate writes meanb

    // ---- input conversion (independent of CSR build) ----
    convert_x_kernel<<<(N_NODES * 32 / 4 + 255) / 256, 256, 0, stream>>>(x, hXb);
    prep_w_kernel<<<24, 256, 0, stream>>>(Wl1, Wr1, Wl2, Wr2, Wl3, Wr3, Wcat);

    // ---- CSR build ----
    hipMemsetAsync(cnt, 0, N_NODES * sizeof(int), stream);
    degree_rank_kernel<<<(N_EDGES + 255) / 256, 256, 0, stream>>>(dst, cnt, rank);
    scan1_kernel<<<N_SCAN_BLOCKS, SCAN_BLOCK, 0, stream>>>(cnt, rowptr, bsum);
    scan2_kernel<<<1, 512, 0, stream>>>(bsum);
    scan3_kernel<<<N_SCAN_BLOCKS, SCAN_BLOCK, 0, stream>>>(cnt, rowptr, bsum, inv);
    permute_kernel<<<(N_EDGES + 255) / 256, 256, 0, stream>>>(src, dst, rank, rowptr, esrc);

    // ---- layer 1 ----
    aggregate_kernel<<<AGG_BLOCKS, 256, 0, stream>>>(rowptr, esrc, inv, hXb, meanb, N_NODES);
    dense_kernel<<<512, 256, 0, stream>>>(meanb, hXb, Wcat, bl1, hAb, N_NODES, 0);
    // ---- layer 2 ----
    aggregate_kernel<<<AGG_BLOCKS, 256, 0, stream>>>(rowptr, esrc, inv, hAb, meanb, N_NODES);
    dense_kernel<<<512, 256, 0, stream>>>(meanb, hAb, Wcat + 2048, bl2, hBb, N_NODES, 0);
    // ---- layer 3: only nodes < N_AGENTS needed ----
    aggregate_kernel<<<(N_AGENTS + 3) / 4, 256, 0, stream>>>(rowptr, esrc, inv, hBb, meanb, N_AGENTS);
    dense_kernel<<<16, 256, 0, stream>>>(meanb, hBb, Wcat + 4096, bl3, h3f, N_AGENTS, 1);
    out_proj_kernel<<<(N_AGENTS + 31) / 32, 256, 0, stream>>>(h3f, Wout, bout, out);
}